// Round 4
// baseline (447.237 us; speedup 1.0000x reference)
//
#include <hip/hip_runtime.h>
#include <math.h>

#define H 256
#define L 50
#define V 50257
#define MAGIC 0x5F3C7A19u

// ---- kernel 1 grid layout (producers at LOWEST indices) ----
#define COMB_NB 64
#define FB_B0   64
#define FB_NB   128
#define G1_B0   192
#define G1_NB   64
#define SW_B0   256
#define SW_NB   640          // 640 blk * 4 waves * 20 rows = 51200 >= V
#define NBLK1   (SW_B0 + SW_NB)   // 896  <= 1024 co-resident (launch_bounds(256,4))
#define ROWS    20
#define HOLD    12           // rows prefetched into regs before h1 spin (48 VGPR)
#define NPART   SW_NB

// ---- kernel 2 ----
#define FINAL_BLKS 197       // 197*256 = 50432 >= V
#define H2_NB      64
#define NBLK2      (FINAL_BLKS + H2_NB)

__device__ __forceinline__ float dot4(float4 a, float4 b) {
    return a.x * b.x + a.y * b.y + a.z * b.z + a.w * b.w;
}

__device__ __forceinline__ float wave_reduce_sum(float v) {
#pragma unroll
    for (int m = 32; m >= 1; m >>= 1) v += __shfl_xor(v, m, 64);
    return v;
}

__device__ __forceinline__ float wave_reduce_max(float v) {
#pragma unroll
    for (int m = 32; m >= 1; m >>= 1) v = fmaxf(v, __shfl_xor(v, m, 64));
    return v;
}

__device__ __forceinline__ float sigmoidf(float x) { return 1.0f / (1.0f + __expf(-x)); }

// device(agent)-scope atomics: cross-XCD-visible producer/consumer traffic
__device__ __forceinline__ void st_flag(unsigned* p, unsigned v) {
    __hip_atomic_store(p, v, __ATOMIC_RELEASE, __HIP_MEMORY_SCOPE_AGENT);
}
__device__ __forceinline__ unsigned ld_flag(const unsigned* p) {
    return __hip_atomic_load(p, __ATOMIC_ACQUIRE, __HIP_MEMORY_SCOPE_AGENT);
}
__device__ __forceinline__ void st_f(float* p, float v) {
    __hip_atomic_store(p, v, __ATOMIC_RELAXED, __HIP_MEMORY_SCOPE_AGENT);
}
__device__ __forceinline__ float ld_f(const float* p) {
    return __hip_atomic_load(p, __ATOMIC_RELAXED, __HIP_MEMORY_SCOPE_AGENT);
}

// online-softmax helpers (guarded against empty (-inf,0) states)
__device__ __forceinline__ void ms_push(float& m, float& s, float x) {
    float mn = fmaxf(m, x);
    s = s * __expf(m - mn) + __expf(x - mn);
    m = mn;
}
__device__ __forceinline__ void ms_merge(float& m, float& s, float om, float os) {
    float M = fmaxf(m, om);
    float a = (m == -INFINITY) ? 0.f : s * __expf(m - M);
    float c = (om == -INFINITY) ? 0.f : os * __expf(om - M);
    m = M; s = a + c;
}

// One GRU output element j computed by one wave. Output via agent-scope store.
__device__ __forceinline__ void gru_wave(
    int j, int lane, float4 xv, float4 hv, float hj,
    const float* __restrict__ w_ih, const float* __restrict__ w_hh,
    const float* __restrict__ b_ih, const float* __restrict__ b_hh,
    float* __restrict__ outp)
{
    float gi[3], gh[3];
#pragma unroll
    for (int k = 0; k < 3; ++k) {
        int row = k * H + j;
        const float4* wi4 = (const float4*)(w_ih + (size_t)row * H);
        const float4* wh4 = (const float4*)(w_hh + (size_t)row * H);
        gi[k] = wave_reduce_sum(dot4(wi4[lane], xv)) + b_ih[row];
        gh[k] = wave_reduce_sum(dot4(wh4[lane], hv)) + b_hh[row];
    }
    if (lane == 0) {
        float r = sigmoidf(gi[0] + gh[0]);
        float z = sigmoidf(gi[1] + gh[1]);
        float n = tanhf(gi[2] + r * gh[2]);
        st_f(outp + j, (1.f - z) * n + z * hj);
    }
}

// ==== K1: chain (comb->fb->g1, flag-ordered) + logits sweep ==================
// launch_bounds(256,4) caps VGPR at 128 -> >=4 blocks/CU -> all 896 blocks
// co-resident by construction -> acyclic flag waits cannot deadlock.
// Sweep blocks prefetch HOLD out_W rows into regs BEFORE spinning on h1, so
// ~31MB of the 51.5MB out_W stream overlaps the GRU chain. Sweep blocks write
// their partial and RETIRE (no all-to-all wait; fold is kernel 2's job).
__global__ __launch_bounds__(256, 4) void k_fused(
    const int* __restrict__ token, const float* __restrict__ hidden,
    const float* __restrict__ enc, const float* __restrict__ emb,
    const float* __restrict__ attn_W, const float* __restrict__ attn_b,
    const float* __restrict__ comb_W, const float* __restrict__ comb_b,
    const float* __restrict__ w_ih_f, const float* __restrict__ w_hh_f,
    const float* __restrict__ b_ih_f, const float* __restrict__ b_hh_f,
    const float* __restrict__ w_ih_b, const float* __restrict__ w_hh_b,
    const float* __restrict__ b_ih_b, const float* __restrict__ b_hh_b,
    const float* __restrict__ w_ih_g, const float* __restrict__ w_hh_g,
    const float* __restrict__ b_ih_g, const float* __restrict__ b_hh_g,
    const float* __restrict__ out_W, const float* __restrict__ out_b,
    float* __restrict__ out_logp, float* __restrict__ out_aw,
    float* __restrict__ ws_x, float* __restrict__ ws_hf,
    float* __restrict__ ws_hb, float* __restrict__ ws_h1,
    float* __restrict__ part_m, float* __restrict__ part_s,
    unsigned* __restrict__ flags)
{
    __shared__ float smem[576];
    int t = threadIdx.x, wid = t >> 6, lane = t & 63;
    int b = blockIdx.x;
    unsigned* fx  = flags;           // 64  (x ready, per comb block)
    unsigned* ffb = flags + 64;      // 128 (hf/hb ready, per fb block)
    unsigned* fh1 = flags + 192;     // 64  (h1 ready, per g1 block)

    if (b >= SW_B0) {
        // ================= logits sweep (640 blocks) =================
        int sid = b - SW_B0;
        int base = (sid * 4 + wid) * ROWS;     // wave's first vocab row
        // prefetch HOLD rows into registers NOW (clamped: always in-bounds)
        float4 hld[HOLD];
#pragma unroll
        for (int k = 0; k < HOLD; ++k) {
            int vc = base + k; if (vc > V - 1) vc = V - 1;
            hld[k] = ((const float4*)(out_W + (size_t)vc * H))[lane];
        }
        __builtin_amdgcn_sched_barrier(0);     // loads stay issued before spin
        float* s_h1 = smem;                    // 256
        float* s_m4 = smem + 256;              // 4
        float* s_s4 = smem + 260;              // 4
        if (t < 64) {
            while (ld_flag(fh1 + t) != MAGIC) __builtin_amdgcn_s_sleep(1);
        }
        __syncthreads();
        s_h1[t] = ld_f(ws_h1 + t);
        __syncthreads();
        float4 hv = ((const float4*)s_h1)[lane];
        float m = -INFINITY, s = 0.f;
#pragma unroll
        for (int k = 0; k < HOLD; ++k) {
            int v = base + k;
            float x0 = wave_reduce_sum(dot4(hld[k], hv));
            if (v < V) {
                x0 += out_b[v];
                if (lane == 0) out_logp[v] = x0;
                ms_push(m, s, x0);
            }
        }
#pragma unroll 2
        for (int k = HOLD; k < ROWS; ++k) {
            int v = base + k; int vc = (v > V - 1) ? V - 1 : v;
            float4 a = ((const float4*)(out_W + (size_t)vc * H))[lane];
            float x0 = wave_reduce_sum(dot4(a, hv));
            if (v < V) {
                x0 += out_b[v];
                if (lane == 0) out_logp[v] = x0;
                ms_push(m, s, x0);
            }
        }
        if (lane == 0) { s_m4[wid] = m; s_s4[wid] = s; }
        __syncthreads();
        if (t == 0) {
            float M = s_m4[0], S = s_s4[0];
#pragma unroll
            for (int q = 1; q < 4; ++q) ms_merge(M, S, s_m4[q], s_s4[q]);
            part_m[sid] = M; part_s[sid] = S;   // kernel boundary orders these
        }
        return;
    }

    if (b < COMB_NB) {
        // ====== fused scores + softmax + applied + comb (64 blocks) ======
        float* s_cat = smem;          // 512
        float* s_aw  = smem + 512;    // 64
        int tok = token[0];
        s_cat[t] = emb[(size_t)tok * H + t];   // e
        s_cat[H + t] = hidden[t];              // h0
        __syncthreads();
        const float4* c4 = (const float4*)s_cat;
        float4 cA = c4[lane];
        float4 cB = c4[lane + 64];
        for (int r = wid; r < L; r += 4) {
            const float4* W4 = (const float4*)(attn_W + (size_t)r * 2 * H);
            float acc = dot4(W4[lane], cA) + dot4(W4[lane + 64], cB);
            acc = wave_reduce_sum(acc);
            if (lane == 0) s_aw[r] = fmaxf(acc + attn_b[r], 0.f);
        }
        __syncthreads();
        if (t < 64) {   // softmax over 50 in wave 0
            float v = (t < L) ? s_aw[t] : -INFINITY;
            float mx = wave_reduce_max(v);
            float e = (t < L) ? __expf(v - mx) : 0.f;
            float ssum = wave_reduce_sum(e);
            if (t < L) {
                float aw = e / ssum;
                s_aw[t] = aw;
                if (b == 0) out_aw[t] = aw;    // third output
            }
        }
        __syncthreads();
        float app = 0.f;
        for (int l = 0; l < L; ++l) app += s_aw[l] * enc[l * H + t];
        s_cat[H + t] = app;                    // overwrite h0 with applied
        __syncthreads();
        int row = b * 4 + wid;
        const float4* Wc = (const float4*)(comb_W + (size_t)row * 2 * H);
        float acc = dot4(Wc[lane], cA) + dot4(Wc[lane + 64], c4[lane + 64]);
        acc = wave_reduce_sum(acc);
        if (lane == 0) st_f(ws_x + row, fmaxf(acc + comb_b[row], 0.f));
        __syncthreads();
        if (t == 0) { __threadfence(); st_flag(fx + b, MAGIC); }
        return;
    }

    if (b < G1_B0) {
        // ========= bidirectional GRU hf/hb (128 blocks) =========
        float* s_x = smem;            // 256
        if (t < 64) {
            while (ld_flag(fx + t) != MAGIC) __builtin_amdgcn_s_sleep(1);
        }
        __syncthreads();
        s_x[t] = ld_f(ws_x + t);
        __syncthreads();
        int g = (b - FB_B0) * 4 + wid;
        int dir = g >> 8, j = g & 255;
        gru_wave(j, lane, ((const float4*)s_x)[lane], ((const float4*)hidden)[lane],
                 hidden[j],
                 dir ? w_ih_b : w_ih_f, dir ? w_hh_b : w_hh_f,
                 dir ? b_ih_b : b_ih_f, dir ? b_hh_b : b_hh_f,
                 dir ? ws_hb : ws_hf);
        __syncthreads();
        if (t == 0) { __threadfence(); st_flag(ffb + (b - FB_B0), MAGIC); }
        return;
    }

    {
        // ========= h1 = GRU(hf, mean(hf,hb)) (64 blocks) =========
        float* s_hf = smem;           // 256
        float* s_hb = smem + 256;     // 256
        if (t < 128) {
            while (ld_flag(ffb + t) != MAGIC) __builtin_amdgcn_s_sleep(1);
        }
        __syncthreads();
        s_hf[t] = ld_f(ws_hf + t);
        s_hb[t] = ld_f(ws_hb + t);
        __syncthreads();
        int j = (b - G1_B0) * 4 + wid;
        float4 fv = ((const float4*)s_hf)[lane];
        float4 bv = ((const float4*)s_hb)[lane];
        float4 hv = make_float4(0.5f * (fv.x + bv.x), 0.5f * (fv.y + bv.y),
                                0.5f * (fv.z + bv.z), 0.5f * (fv.w + bv.w));
        float hj = 0.5f * (s_hf[j] + s_hb[j]);
        gru_wave(j, lane, fv, hv, hj, w_ih_g, w_hh_g, b_ih_g, b_hh_g, ws_h1);
        __syncthreads();
        if (t == 0) { __threadfence(); st_flag(fh1 + (b - G1_B0), MAGIC); }
        return;
    }
}

// ==== K2: fold partials -> lse; subtract (blocks 0..196) ====================
//          + h2 = GRU(hb, h1) on tail blocks (off critical path).
// No cross-block waits anywhere -> no deadlock mode.
__global__ __launch_bounds__(256) void k_final(
    const float* __restrict__ part_m, const float* __restrict__ part_s,
    float* __restrict__ logits,
    const float* __restrict__ h1, const float* __restrict__ hb,
    const float* __restrict__ w_ih_g, const float* __restrict__ w_hh_g,
    const float* __restrict__ b_ih_g, const float* __restrict__ b_hh_g,
    float* __restrict__ out_h2)
{
    int t = threadIdx.x, wid = t >> 6, lane = t & 63;
    if (blockIdx.x >= FINAL_BLKS) {           // uniform per block
        int j = (blockIdx.x - FINAL_BLKS) * 4 + wid;
        gru_wave(j, lane, ((const float4*)hb)[lane], ((const float4*)h1)[lane],
                 h1[j], w_ih_g, w_hh_g, b_ih_g, b_hh_g, out_h2);
        return;
    }
    __shared__ float s_m4[4], s_s4[4];
    __shared__ float s_bcast;
    float m = -INFINITY, s = 0.f;
    for (int idx = t; idx < NPART; idx += 256)
        ms_merge(m, s, part_m[idx], part_s[idx]);
#pragma unroll
    for (int d = 32; d >= 1; d >>= 1) {
        float om = __shfl_xor(m, d, 64);
        float os = __shfl_xor(s, d, 64);
        ms_merge(m, s, om, os);
    }
    if (lane == 0) { s_m4[wid] = m; s_s4[wid] = s; }
    __syncthreads();
    if (t == 0) {
        float M = s_m4[0], S = s_s4[0];
#pragma unroll
        for (int q = 1; q < 4; ++q) ms_merge(M, S, s_m4[q], s_s4[q]);
        s_bcast = M + logf(S);
    }
    __syncthreads();
    float lse = s_bcast;
    int i = blockIdx.x * 256 + t;
    if (i < V) logits[i] -= lse;
}

extern "C" void kernel_launch(void* const* d_in, const int* in_sizes, int n_in,
                              void* d_out, int out_size, void* d_ws, size_t ws_size,
                              hipStream_t stream)
{
    const int*   token  = (const int*)d_in[0];
    const float* hidden = (const float*)d_in[1];
    const float* enc    = (const float*)d_in[2];
    const float* emb    = (const float*)d_in[3];
    const float* attn_W = (const float*)d_in[4];
    const float* attn_b = (const float*)d_in[5];
    const float* comb_W = (const float*)d_in[6];
    const float* comb_b = (const float*)d_in[7];
    const float* w_ih_f = (const float*)d_in[8];
    const float* w_hh_f = (const float*)d_in[9];
    const float* b_ih_f = (const float*)d_in[10];
    const float* b_hh_f = (const float*)d_in[11];
    const float* w_ih_b = (const float*)d_in[12];
    const float* w_hh_b = (const float*)d_in[13];
    const float* b_ih_b = (const float*)d_in[14];
    const float* b_hh_b = (const float*)d_in[15];
    const float* w_ih_g = (const float*)d_in[16];
    const float* w_hh_g = (const float*)d_in[17];
    const float* b_ih_g = (const float*)d_in[18];
    const float* b_hh_g = (const float*)d_in[19];
    const float* out_W  = (const float*)d_in[20];
    const float* out_b  = (const float*)d_in[21];

    float* out = (float*)d_out;   // [V logp | H h2 | L aw]
    float* ws  = (float*)d_ws;
    // ws layout (floats): x[256] hf[256] hb[256] h1[256] part_m[640] part_s[640]
    //                     then 256 uint flags
    float* ws_x   = ws;
    float* ws_hf  = ws + 256;
    float* ws_hb  = ws + 512;
    float* ws_h1  = ws + 768;
    float* part_m = ws + 1024;
    float* part_s = ws + 1664;
    unsigned* flags = (unsigned*)(ws + 2304);

    k_fused<<<NBLK1, 256, 0, stream>>>(
        token, hidden, enc, emb, attn_W, attn_b, comb_W, comb_b,
        w_ih_f, w_hh_f, b_ih_f, b_hh_f, w_ih_b, w_hh_b, b_ih_b, b_hh_b,
        w_ih_g, w_hh_g, b_ih_g, b_hh_g, out_W, out_b,
        out, out + V + H,
        ws_x, ws_hf, ws_hb, ws_h1, part_m, part_s, flags);
    k_final<<<NBLK2, 256, 0, stream>>>(
        part_m, part_s, out, ws_h1, ws_hb,
        w_ih_g, w_hh_g, b_ih_g, b_hh_g, out + V);
}

// Round 5
// 179.190 us; speedup vs baseline: 2.4959x; 2.4959x over previous
//
#include <hip/hip_runtime.h>
#include <math.h>

#define H 256
#define L 50
#define V 50257
#define LOGIT_BLKS 786   // 786 blk * 4 waves * 16 rows = 50304 >= V

__device__ __forceinline__ float dot4(float4 a, float4 b) {
    return a.x * b.x + a.y * b.y + a.z * b.z + a.w * b.w;
}

__device__ __forceinline__ float wave_reduce_sum(float v) {
#pragma unroll
    for (int m = 32; m >= 1; m >>= 1) v += __shfl_xor(v, m, 64);
    return v;
}

__device__ __forceinline__ float wave_reduce_max(float v) {
#pragma unroll
    for (int m = 32; m >= 1; m >>= 1) v = fmaxf(v, __shfl_xor(v, m, 64));
    return v;
}

__device__ __forceinline__ float sigmoidf(float x) { return 1.0f / (1.0f + __expf(-x)); }

// online-softmax helpers (guarded against empty (-inf,0) states)
__device__ __forceinline__ void ms_push(float& m, float& s, float x) {
    float mn = fmaxf(m, x);
    s = s * __expf(m - mn) + __expf(x - mn);
    m = mn;
}
__device__ __forceinline__ void ms_merge(float& m, float& s, float om, float os) {
    float M = fmaxf(m, om);
    float a = (m == -INFINITY) ? 0.f : s * __expf(m - M);
    float c = (om == -INFINITY) ? 0.f : os * __expf(om - M);
    m = M; s = a + c;
}

// One GRU output element j computed by one wave.
__device__ __forceinline__ void gru_wave(
    int j, int lane, float4 xv, float4 hv, float hj,
    const float* __restrict__ w_ih, const float* __restrict__ w_hh,
    const float* __restrict__ b_ih, const float* __restrict__ b_hh,
    float* __restrict__ outp)
{
    float gi[3], gh[3];
#pragma unroll
    for (int k = 0; k < 3; ++k) {
        int row = k * H + j;
        const float4* wi4 = (const float4*)(w_ih + (size_t)row * H);
        const float4* wh4 = (const float4*)(w_hh + (size_t)row * H);
        gi[k] = wave_reduce_sum(dot4(wi4[lane], xv)) + b_ih[row];
        gh[k] = wave_reduce_sum(dot4(wh4[lane], hv)) + b_hh[row];
    }
    if (lane == 0) {
        float r = sigmoidf(gi[0] + gh[0]);
        float z = sigmoidf(gi[1] + gh[1]);
        float n = tanhf(gi[2] + r * gh[2]);
        outp[j] = (1.f - z) * n + z * hj;
    }
}

// ---- K1: scores[l] = relu(attn_W[l,:] . [e|h0] + attn_b[l]), 13 blocks ----
__global__ __launch_bounds__(256) void k_scores(
    const int* __restrict__ token, const float* __restrict__ hidden,
    const float* __restrict__ emb, const float* __restrict__ attn_W,
    const float* __restrict__ attn_b, float* __restrict__ ws_scores)
{
    __shared__ float s_vec[2 * H];
    int t = threadIdx.x, wid = t >> 6, lane = t & 63;
    int tok = token[0];
    s_vec[t] = emb[(size_t)tok * H + t];
    s_vec[H + t] = hidden[t];
    __syncthreads();
    int row = blockIdx.x * 4 + wid;
    if (row < L) {
        float acc = 0.f;
#pragma unroll
        for (int c = 0; c < 8; ++c)
            acc += attn_W[row * 2 * H + c * 64 + lane] * s_vec[c * 64 + lane];
        acc = wave_reduce_sum(acc);
        if (lane == 0) ws_scores[row] = fmaxf(acc + attn_b[row], 0.f);
    }
}

// ---- K2: softmax(scores) -> aw; applied = aw@enc; x = relu(comb_W@[e|applied]+b)
// 64 blocks; softmax+applied replicated per block (tiny, L2-hot). -------------
__global__ __launch_bounds__(256) void k_comb(
    const int* __restrict__ token, const float* __restrict__ emb,
    const float* __restrict__ enc, const float* __restrict__ comb_W,
    const float* __restrict__ comb_b, const float* __restrict__ ws_scores,
    float* __restrict__ ws_x, float* __restrict__ out_aw)
{
    __shared__ __align__(16) float s_cat[2 * H];
    __shared__ float s_aw[64];
    int t = threadIdx.x, wid = t >> 6, lane = t & 63;
    int tok = token[0];
    s_cat[t] = emb[(size_t)tok * H + t];      // e
    if (t < 64) {  // softmax over 50 in wave 0
        float v = (t < L) ? ws_scores[t] : -INFINITY;
        float mx = wave_reduce_max(v);
        float e = (t < L) ? __expf(v - mx) : 0.f;
        float ssum = wave_reduce_sum(e);
        if (t < L) {
            float aw = e / ssum;
            s_aw[t] = aw;
            if (blockIdx.x == 0) out_aw[t] = aw;   // third output
        }
    }
    __syncthreads();
    float app = 0.f;
    for (int l = 0; l < L; ++l) app += s_aw[l] * enc[l * H + t];
    s_cat[H + t] = app;
    __syncthreads();
    int row = blockIdx.x * 4 + wid;
    const float4* c4 = (const float4*)s_cat;
    const float4* W4 = (const float4*)(comb_W + (size_t)row * 2 * H);
    float acc = dot4(W4[lane], c4[lane]) + dot4(W4[lane + 64], c4[lane + 64]);
    acc = wave_reduce_sum(acc);
    if (lane == 0) ws_x[row] = fmaxf(acc + comb_b[row], 0.f);
}

// ---- K3: bidirectional GRU (hf, hb), 128 blocks, wave per (dir, j) ----------
__global__ __launch_bounds__(256) void k_gru_fb(
    const float* __restrict__ ws_x, const float* __restrict__ hidden,
    const float* __restrict__ w_ih_f, const float* __restrict__ w_hh_f,
    const float* __restrict__ b_ih_f, const float* __restrict__ b_hh_f,
    const float* __restrict__ w_ih_b, const float* __restrict__ w_hh_b,
    const float* __restrict__ b_ih_b, const float* __restrict__ b_hh_b,
    float* __restrict__ ws_hf, float* __restrict__ ws_hb)
{
    int t = threadIdx.x, wid = t >> 6, lane = t & 63;
    int g = blockIdx.x * 4 + wid;
    int dir = g >> 8, j = g & 255;
    gru_wave(j, lane, ((const float4*)ws_x)[lane], ((const float4*)hidden)[lane],
             hidden[j],
             dir ? w_ih_b : w_ih_f, dir ? w_hh_b : w_hh_f,
             dir ? b_ih_b : b_ih_f, dir ? b_hh_b : b_hh_f,
             dir ? ws_hb : ws_hf);
}

// ---- K4/K5: generic GRU cell, 64 blocks; hb!=null -> state = mean(ha,hb) ----
__global__ __launch_bounds__(256) void k_gru(
    const float* __restrict__ xvec, const float* __restrict__ ha,
    const float* __restrict__ hb,
    const float* __restrict__ w_ih, const float* __restrict__ w_hh,
    const float* __restrict__ b_ih, const float* __restrict__ b_hh,
    float* __restrict__ outp)
{
    int t = threadIdx.x, wid = t >> 6, lane = t & 63;
    int j = blockIdx.x * 4 + wid;
    float4 xv = ((const float4*)xvec)[lane];
    float4 hv = ((const float4*)ha)[lane];
    float hj;
    if (hb) {
        float4 bv = ((const float4*)hb)[lane];
        hv = make_float4(0.5f * (hv.x + bv.x), 0.5f * (hv.y + bv.y),
                         0.5f * (hv.z + bv.z), 0.5f * (hv.w + bv.w));
        hj = 0.5f * (ha[j] + hb[j]);
    } else {
        hj = ha[j];
    }
    gru_wave(j, lane, xv, hv, hj, w_ih, w_hh, b_ih, b_hh, outp);
}

// ---- K6: logits + per-block online-softmax partials. 786 blocks ------------
// Wave handles 16 consecutive rows, 2 in flight (12 waves/CU * 2KB in flight
// covers the BW*latency product for ~6 TB/s).
__global__ __launch_bounds__(256) void k_logits(
    const float* __restrict__ out_W, const float* __restrict__ out_b,
    const float* __restrict__ h1, float* __restrict__ logits,
    float* __restrict__ part_m, float* __restrict__ part_s)
{
    __shared__ float s_m4[4], s_s4[4];
    int t = threadIdx.x, wid = t >> 6, lane = t & 63;
    float4 hv = ((const float4*)h1)[lane];
    int base = (blockIdx.x * 4 + wid) * 16;
    float m = -INFINITY, s = 0.f;
#pragma unroll 1
    for (int k = 0; k < 16; k += 2) {
        int v = base + k;
        if (v >= V) break;
        const float4* W0 = (const float4*)(out_W + (size_t)v * H);
        float4 a0 = W0[lane];
        bool has2 = (v + 1 < V);
        float4 a1 = has2 ? ((const float4*)(out_W + (size_t)(v + 1) * H))[lane]
                         : make_float4(0.f, 0.f, 0.f, 0.f);
        float x0 = wave_reduce_sum(dot4(a0, hv)) + out_b[v];
        float x1 = wave_reduce_sum(dot4(a1, hv));
        if (lane == 0) logits[v] = x0;
        ms_push(m, s, x0);
        if (has2) {
            x1 += out_b[v + 1];
            if (lane == 0) logits[v + 1] = x1;
            ms_push(m, s, x1);
        }
    }
    if (lane == 0) { s_m4[wid] = m; s_s4[wid] = s; }
    __syncthreads();
    if (t == 0) {
        float M = s_m4[0], S = s_s4[0];
#pragma unroll
        for (int q = 1; q < 4; ++q) ms_merge(M, S, s_m4[q], s_s4[q]);
        part_m[blockIdx.x] = M; part_s[blockIdx.x] = S;
    }
}

// ---- K7: fold 786 partials -> lse (replicated per block); subtract ---------
__global__ __launch_bounds__(256) void k_final(
    const float* __restrict__ part_m, const float* __restrict__ part_s,
    float* __restrict__ logits)
{
    __shared__ float s_m4[4], s_s4[4];
    __shared__ float s_bcast;
    int t = threadIdx.x, wid = t >> 6, lane = t & 63;
    float m = -INFINITY, s = 0.f;
    for (int idx = t; idx < LOGIT_BLKS; idx += 256)
        ms_merge(m, s, part_m[idx], part_s[idx]);
#pragma unroll
    for (int d = 32; d >= 1; d >>= 1) {
        float om = __shfl_xor(m, d, 64);
        float os = __shfl_xor(s, d, 64);
        ms_merge(m, s, om, os);
    }
    if (lane == 0) { s_m4[wid] = m; s_s4[wid] = s; }
    __syncthreads();
    if (t == 0) {
        float M = s_m4[0], S = s_s4[0];
#pragma unroll
        for (int q = 1; q < 4; ++q) ms_merge(M, S, s_m4[q], s_s4[q]);
        s_bcast = M + logf(S);
    }
    __syncthreads();
    float lse = s_bcast;
    int i = blockIdx.x * 256 + t;
    if (i < V) logits[i] -= lse;
}

extern "C" void kernel_launch(void* const* d_in, const int* in_sizes, int n_in,
                              void* d_out, int out_size, void* d_ws, size_t ws_size,
                              hipStream_t stream)
{
    const int*   token  = (const int*)d_in[0];
    const float* hidden = (const float*)d_in[1];
    const float* enc    = (const float*)d_in[2];
    const float* emb    = (const float*)d_in[3];
    const float* attn_W = (const float*)d_in[4];
    const float* attn_b = (const float*)d_in[5];
    const float* comb_W = (const float*)d_in[6];
    const float* comb_b = (const float*)d_in[7];
    const float* w_ih_f = (const float*)d_in[8];
    const float* w_hh_f = (const float*)d_in[9];
    const float* b_ih_f = (const float*)d_in[10];
    const float* b_hh_f = (const float*)d_in[11];
    const float* w_ih_b = (const float*)d_in[12];
    const float* w_hh_b = (const float*)d_in[13];
    const float* b_ih_b = (const float*)d_in[14];
    const float* b_hh_b = (const float*)d_in[15];
    const float* w_ih_g = (const float*)d_in[16];
    const float* w_hh_g = (const float*)d_in[17];
    const float* b_ih_g = (const float*)d_in[18];
    const float* b_hh_g = (const float*)d_in[19];
    const float* out_W  = (const float*)d_in[20];
    const float* out_b  = (const float*)d_in[21];

    float* out = (float*)d_out;   // [V logp | H h2 | L aw]
    float* ws  = (float*)d_ws;
    float* ws_scores = ws;            // 64
    float* ws_x      = ws + 64;       // 256
    float* ws_hf     = ws + 320;      // 256
    float* ws_hb     = ws + 576;      // 256
    float* ws_h1     = ws + 832;      // 256
    float* part_m    = ws + 1088;     // 786
    float* part_s    = ws + 1888;     // 786

    k_scores<<<13, 256, 0, stream>>>(token, hidden, emb, attn_W, attn_b, ws_scores);
    k_comb<<<64, 256, 0, stream>>>(token, emb, enc, comb_W, comb_b, ws_scores,
                                   ws_x, out + V + H);
    k_gru_fb<<<128, 256, 0, stream>>>(ws_x, hidden,
                                      w_ih_f, w_hh_f, b_ih_f, b_hh_f,
                                      w_ih_b, w_hh_b, b_ih_b, b_hh_b,
                                      ws_hf, ws_hb);
    k_gru<<<64, 256, 0, stream>>>(ws_hf, ws_hf, ws_hb,
                                  w_ih_g, w_hh_g, b_ih_g, b_hh_g, ws_h1);
    k_gru<<<64, 256, 0, stream>>>(ws_hb, ws_h1, nullptr,
                                  w_ih_g, w_hh_g, b_ih_g, b_hh_g, out + V);
    k_logits<<<LOGIT_BLKS, 256, 0, stream>>>(out_W, out_b, ws_h1, out,
                                             part_m, part_s);
    k_final<<<197, 256, 0, stream>>>(part_m, part_s, out);
}